// Round 6
// baseline (876.489 us; speedup 1.0000x reference)
//
#include <hip/hip_runtime.h>
#include <cmath>

#define NPT 1024
#define NB 32
#define IN_DIM 36
#define HDIM 128
#define HPAD 132          // +4 floats: rows land in different banks, keeps 16B align
#define OUT_DIM 48
#define TOPK 13           // K+1; first (self) dropped
#define PTILE 8           // points per MLP block
#define QB 64             // queries per KNN block
#define NSL 4             // candidate slices per query
#define SLICE (NPT / NSL) // 256

typedef float f4 __attribute__((ext_vector_type(4)));
typedef unsigned long long ull;

__device__ __forceinline__ unsigned mono(float d) {
    unsigned f = __float_as_uint(d);
    return (f & 0x80000000u) ? ~f : (f | 0x80000000u);
}

// ---------------- Stage 0: pre-masked MADE weights into workspace ----------------
// m2[i][j] = (j%7 >= i%7); mo[i][o] = (o/6 > i%7). Re-run every launch (ws re-poisoned).
__global__ __launch_bounds__(256) void premask_kernel(const float* __restrict__ mw2,
                                                      const float* __restrict__ mwo,
                                                      float* __restrict__ mw2m,
                                                      float* __restrict__ mwom) {
    int t = blockIdx.x * 256 + threadIdx.x;
    if (t < HDIM * HDIM) {
        int i = t >> 7, j = t & 127;
        mw2m[t] = ((j % 7) >= (i % 7)) ? mw2[t] : 0.0f;
    }
    if (t < HDIM * OUT_DIM) {
        int i = t / OUT_DIM, o = t - i * OUT_DIM;
        mwom[t] = ((o / 6) > (i % 7)) ? mwo[t] : 0.0f;
    }
}

// ---------------- Stage A: KNN + local-frame gather ----------------
// 256 threads = 4 waves; wave w scans candidate slice [256w,256w+256) for 64 queries.
// Key = (monotone(dist) << 32) | idx  -> strict < == (dist, idx) lexicographic,
// identical tie semantics to jax.lax.top_k (lowest index wins).
__global__ __launch_bounds__(256) void knn_kernel(const float* __restrict__ coords,
                                                  float* __restrict__ flat) {
    const int b = blockIdx.y;
    const int q0 = blockIdx.x * QB;
    const int tid = threadIdx.x;
    const int lane = tid & 63;   // query within block
    const int w = tid >> 6;      // slice id

    __shared__ f4 pts[NPT];                    // {x,y,z,|p|^2} 16 KB
    __shared__ ull cand[NSL][QB][TOPK + 1];    // +1 sentinel    28 KB

    const float* cb = coords + (size_t)b * NPT * 3;
    for (int i = tid; i < NPT; i += QB * NSL) {
        float x = cb[3 * i + 0], y = cb[3 * i + 1], z = cb[3 * i + 2];
        f4 v; v[0] = x; v[1] = y; v[2] = z; v[3] = x * x + y * y + z * z;
        pts[i] = v;
    }
    __syncthreads();

    const int q = q0 + lane;
    const f4 C = pts[q];
    const float cx = C[0], cy = C[1], cz = C[2], sq_q = C[3];

    ull best[TOPK];
#pragma unroll
    for (int k = 0; k < TOPK; ++k) best[k] = ~0ull;

    const int jbase = w * SLICE;
    for (int t = 0; t < SLICE; ++t) {
        int j = jbase + t;
        f4 P = pts[j];
        float dot = cx * P[0] + cy * P[1] + cz * P[2];
        float d = sq_q + P[3] - 2.0f * dot;    // reference formula
        ull key = ((ull)mono(d) << 32) | (unsigned)j;
        if (key < best[TOPK - 1]) {
            ull carry = key;
#pragma unroll
            for (int k = 0; k < TOPK; ++k) {
                ull old = best[k];
                ull lo = (old < carry) ? old : carry;
                carry   = (old < carry) ? carry : old;
                best[k] = lo;
            }
        }
    }
#pragma unroll
    for (int k = 0; k < TOPK; ++k) cand[w][lane][k] = best[k];
    cand[w][lane][TOPK] = ~0ull;   // sentinel
    __syncthreads();

    // 4-way merge, one thread per query (wave 0)
    if (tid < QB) {
        const int mq = tid;
        const f4 MC = pts[q0 + mq];
        float* o = flat + (size_t)(b * NPT + q0 + mq) * IN_DIM;
        int h0 = 0, h1 = 0, h2 = 0, h3 = 0;
        for (int k = 0; k < TOPK; ++k) {
            ull v0 = cand[0][mq][h0], v1 = cand[1][mq][h1];
            ull v2 = cand[2][mq][h2], v3 = cand[3][mq][h3];
            ull m01 = v0 < v1 ? v0 : v1;
            ull m23 = v2 < v3 ? v2 : v3;
            ull m = m01 < m23 ? m01 : m23;
            h0 += (v0 == m); h1 += (v1 == m); h2 += (v2 == m); h3 += (v3 == m);
            if (k > 0) {                         // k==0 matches reference idx[:,:,1:] drop
                int j = (int)(m & 0xFFFFFFFFull);
                f4 P = pts[j];
                o[(k - 1) * 3 + 0] = P[0] - MC[0];
                o[(k - 1) * 3 + 1] = P[1] - MC[1];
                o[(k - 1) * 3 + 2] = P[2] - MC[2];
            }
        }
    }
}

// ---------------- Stage B: fused MLP + MADE + combine ----------------
// 128 threads, PTILE=8 points. Main layers: thread = (pg 0..3)x(ng 0..31),
// tile MP=2 points x NJ=4 neurons, both h- and g-paths. LDS reads are b128,
// broadcast within 32-lane groups -> LDS pipe ~1/4 of VALU time.
// PM=true: MADE weights pre-masked in ws. PM=false: mask applied inline.
template <bool PM>
__global__ __launch_bounds__(128, 4) void mlp_kernel(
    const float* __restrict__ flat, const float* __restrict__ coords,
    const float* __restrict__ w_h1, const float* __restrict__ b_h1,
    const float* __restrict__ w_h2, const float* __restrict__ b_h2,
    const float* __restrict__ w_h3, const float* __restrict__ b_h3,
    const float* __restrict__ w_bp, const float* __restrict__ b_bp,
    const float* __restrict__ cw,  const float* __restrict__ mb1,
    const float* __restrict__ mw2x, const float* __restrict__ mb2,
    const float* __restrict__ mwox, const float* __restrict__ mbo,
    float* __restrict__ out) {
    const int p0g = blockIdx.x * PTILE;
    const int tid = threadIdx.x;
    const int ng = tid & 31, pg = tid >> 5;
    const int j0 = ng * 4;
    const int pA = pg * 2;

    __shared__ float A[PTILE][HPAD];   // hA, then h3
    __shared__ float B[PTILE][HPAD];   // gA (tanh layer1)
    __shared__ float Cb[PTILE][HPAD];  // x (aliased), then hB
    __shared__ float D[PTILE][HPAD];   // gB

    // stage x into Cb's space (dead before Cb is written in layer 2)
    float* xbuf = &Cb[0][0];           // [PTILE][IN_DIM] packed
    {
        const f4* src = (const f4*)(flat + (size_t)p0g * IN_DIM);
        f4* dst = (f4*)xbuf;
        for (int u = tid; u < PTILE * IN_DIM / 4; u += 128) dst[u] = src[u];
    }
    __syncthreads();

    f4 acch[2], accg[2];

    // ---- layer 1 (h) + MADE layer 1 (g): input dim 36 ----
    {
        f4 bh = *(const f4*)&b_h1[j0];
        f4 bg = *(const f4*)&mb1[j0];
        acch[0] = bh; acch[1] = bh; accg[0] = bg; accg[1] = bg;
        for (int i = 0; i < IN_DIM; i += 4) {
            f4 xa = *(const f4*)&xbuf[(pA + 0) * IN_DIM + i];
            f4 xb = *(const f4*)&xbuf[(pA + 1) * IN_DIM + i];
#pragma unroll
            for (int u = 0; u < 4; ++u) {
                f4 wh = *(const f4*)&w_h1[(i + u) * HDIM + j0];
                f4 wg = *(const f4*)&cw[(i + u) * HDIM + j0];
                acch[0] += xa[u] * wh; acch[1] += xb[u] * wh;
                accg[0] += xa[u] * wg; accg[1] += xb[u] * wg;
            }
        }
    }
    __syncthreads();   // all xbuf reads done (stores below go to A/B, not Cb)
#pragma unroll
    for (int p = 0; p < 2; ++p) {
        f4 r, g;
#pragma unroll
        for (int u = 0; u < 4; ++u) { r[u] = fmaxf(acch[p][u], 0.0f); g[u] = tanhf(accg[p][u]); }
        *(f4*)&A[pA + p][j0] = r;
        *(f4*)&B[pA + p][j0] = g;
    }
    __syncthreads();

    // ---- layer 2 (h) + masked MADE layer 2 (g) ----
    {
        f4 bh = *(const f4*)&b_h2[j0];
        f4 bg = *(const f4*)&mb2[j0];
        acch[0] = bh; acch[1] = bh; accg[0] = bg; accg[1] = bg;
        for (int i = 0; i < HDIM; i += 4) {
            f4 a0 = *(const f4*)&A[pA + 0][i];
            f4 a1 = *(const f4*)&A[pA + 1][i];
            f4 g0 = *(const f4*)&B[pA + 0][i];
            f4 g1 = *(const f4*)&B[pA + 1][i];
#pragma unroll
            for (int u = 0; u < 4; ++u) {
                f4 wh = *(const f4*)&w_h2[(i + u) * HDIM + j0];
                f4 wg = *(const f4*)&mw2x[(i + u) * HDIM + j0];
                if (!PM) {
                    int r = (i + u) % 7;   // m2[i][j] = (j%7 >= i%7)
#pragma unroll
                    for (int c = 0; c < 4; ++c)
                        wg[c] = (((j0 + c) % 7) >= r) ? wg[c] : 0.0f;
                }
                acch[0] += a0[u] * wh; acch[1] += a1[u] * wh;
                accg[0] += g0[u] * wg; accg[1] += g1[u] * wg;
            }
        }
        __syncthreads();   // all A/B reads done before Cb/D overwrite below
#pragma unroll
        for (int p = 0; p < 2; ++p) {
            f4 r, g;
#pragma unroll
            for (int u = 0; u < 4; ++u) { r[u] = fmaxf(acch[p][u], 0.0f); g[u] = tanhf(accg[p][u]); }
            *(f4*)&Cb[pA + p][j0] = r;
            *(f4*)&D[pA + p][j0] = g;
        }
    }
    __syncthreads();

    // ---- layer 3 (h only): reads Cb, writes A ----
    {
        f4 bh = *(const f4*)&b_h3[j0];
        acch[0] = bh; acch[1] = bh;
        for (int i = 0; i < HDIM; i += 4) {
            f4 a0 = *(const f4*)&Cb[pA + 0][i];
            f4 a1 = *(const f4*)&Cb[pA + 1][i];
#pragma unroll
            for (int u = 0; u < 4; ++u) {
                f4 wh = *(const f4*)&w_h3[(i + u) * HDIM + j0];
                acch[0] += a0[u] * wh; acch[1] += a1[u] * wh;
            }
        }
        __syncthreads();   // orders A overwrite after layer-2 reads
#pragma unroll
        for (int p = 0; p < 2; ++p) {
            f4 r;
#pragma unroll
            for (int u = 0; u < 4; ++u) r[u] = fmaxf(acch[p][u], 0.0f);
            *(f4*)&A[pA + p][j0] = r;
        }
    }
    __syncthreads();

    // ---- heads + combine: thread = (pq 0..7) x (og 0..15), outputs o0..o0+2 ----
    // param from h3 (A), shift from gB (D); same thread holds both -> direct write.
    {
        const int og = tid & 15, pq = tid >> 4;
        const int o0 = og * 3;
        const int dego0 = (o0 + 0) / 6, dego1 = (o0 + 1) / 6, dego2 = (o0 + 2) / 6;
        float ap[3], as[3];
#pragma unroll
        for (int t = 0; t < 3; ++t) { ap[t] = b_bp[o0 + t]; as[t] = mbo[o0 + t]; }
        for (int i = 0; i < HDIM; i += 4) {
            f4 hv = *(const f4*)&A[pq][i];
            f4 gv = *(const f4*)&D[pq][i];
#pragma unroll
            for (int u = 0; u < 4; ++u) {
                float ws0 = mwox[(i + u) * OUT_DIM + o0 + 0];
                float ws1 = mwox[(i + u) * OUT_DIM + o0 + 1];
                float ws2 = mwox[(i + u) * OUT_DIM + o0 + 2];
                if (!PM) {
                    int r = (i + u) % 7;   // mo[i][o] = (o/6 > i%7)
                    ws0 = (dego0 > r) ? ws0 : 0.0f;
                    ws1 = (dego1 > r) ? ws1 : 0.0f;
                    ws2 = (dego2 > r) ? ws2 : 0.0f;
                }
                ap[0] = fmaf(hv[u], w_bp[(i + u) * OUT_DIM + o0 + 0], ap[0]);
                ap[1] = fmaf(hv[u], w_bp[(i + u) * OUT_DIM + o0 + 1], ap[1]);
                ap[2] = fmaf(hv[u], w_bp[(i + u) * OUT_DIM + o0 + 2], ap[2]);
                as[0] = fmaf(gv[u], ws0, as[0]);
                as[1] = fmaf(gv[u], ws1, as[1]);
                as[2] = fmaf(gv[u], ws2, as[2]);
            }
        }
        const float* cpt = &coords[(size_t)(p0g + pq) * 3];
        float c0 = cpt[0], c1 = cpt[1], c2 = cpt[2];
        float* op = out + (size_t)(p0g + pq) * OUT_DIM;
#pragma unroll
        for (int t = 0; t < 3; ++t) {
            int o = o0 + t;
            float v = ap[t] + as[t];
            float r;
            if (o & 1) {
                r = expf(0.5f * v);
            } else {
                int d = (o % 6) >> 1;
                float cv = (d == 0) ? c0 : (d == 1) ? c1 : c2;
                r = cv + v;
            }
            op[o] = r;
        }
    }
}

extern "C" void kernel_launch(void* const* d_in, const int* in_sizes, int n_in,
                              void* d_out, int out_size, void* d_ws, size_t ws_size,
                              hipStream_t stream) {
    const float* coords = (const float*)d_in[0];
    const float* w_h1 = (const float*)d_in[1];
    const float* b_h1 = (const float*)d_in[2];
    const float* w_h2 = (const float*)d_in[3];
    const float* b_h2 = (const float*)d_in[4];
    const float* w_h3 = (const float*)d_in[5];
    const float* b_h3 = (const float*)d_in[6];
    const float* w_bp = (const float*)d_in[7];
    const float* b_bp = (const float*)d_in[8];
    const float* cw   = (const float*)d_in[9];
    // d_in[10] = mw1: dead (x0 == 0)
    const float* mb1  = (const float*)d_in[11];
    const float* mw2  = (const float*)d_in[12];
    const float* mb2  = (const float*)d_in[13];
    const float* mwo  = (const float*)d_in[14];
    const float* mbo  = (const float*)d_in[15];
    float* out = (float*)d_out;

    char* ws = (char*)d_ws;
    const size_t FLAT_BYTES = (size_t)NB * NPT * IN_DIM * 4;      // 4718592
    const size_t MW2M_BYTES = HDIM * HDIM * 4;                    // 65536
    const size_t MWOM_BYTES = HDIM * OUT_DIM * 4;                 // 24576
    float* flat = (float*)ws;
    const bool pm = ws_size >= FLAT_BYTES + MW2M_BYTES + MWOM_BYTES;  // constant per run

    dim3 gA(NPT / QB, NB);
    knn_kernel<<<gA, QB * NSL, 0, stream>>>(coords, flat);

    const int nblocks = (NB * NPT) / PTILE;                 // 4096
    if (pm) {
        float* mw2m = (float*)(ws + FLAT_BYTES);
        float* mwom = (float*)(ws + FLAT_BYTES + MW2M_BYTES);
        premask_kernel<<<(HDIM * HDIM + 255) / 256, 256, 0, stream>>>(mw2, mwo, mw2m, mwom);
        mlp_kernel<true><<<nblocks, 128, 0, stream>>>(flat, coords,
                                                      w_h1, b_h1, w_h2, b_h2, w_h3, b_h3,
                                                      w_bp, b_bp, cw, mb1, mw2m, mb2, mwom, mbo,
                                                      out);
    } else {
        mlp_kernel<false><<<nblocks, 128, 0, stream>>>(flat, coords,
                                                       w_h1, b_h1, w_h2, b_h2, w_h3, b_h3,
                                                       w_bp, b_bp, cw, mb1, mw2, mb2, mwo, mbo,
                                                       out);
    }
}

// Round 13
// 391.597 us; speedup vs baseline: 2.2382x; 2.2382x over previous
//
#include <hip/hip_runtime.h>
#include <cmath>

#define NPT 1024
#define NB 32
#define IN_DIM 36
#define HDIM 128
#define HPAD 132          // +4 floats: 16B-aligned rows, de-phased banks
#define OUT_DIM 48
#define TOPK 13           // K+1; first (self) dropped
#define PTILE 8           // points per MLP block
#define QB 64             // queries per KNN block
#define NSL 4             // candidate slices per query
#define SLICE (NPT / NSL) // 256

typedef float f4 __attribute__((ext_vector_type(4)));
typedef unsigned long long ull;

__device__ __forceinline__ unsigned mono(float d) {
    unsigned f = __float_as_uint(d);
    return (f & 0x80000000u) ? ~f : (f | 0x80000000u);
}

// ---------------- Stage 0: pre-masked MADE weights into workspace ----------------
__global__ __launch_bounds__(256) void premask_kernel(const float* __restrict__ mw2,
                                                      const float* __restrict__ mwo,
                                                      float* __restrict__ mw2m,
                                                      float* __restrict__ mwom) {
    int t = blockIdx.x * 256 + threadIdx.x;
    if (t < HDIM * HDIM) {
        int i = t >> 7, j = t & 127;
        mw2m[t] = ((j % 7) >= (i % 7)) ? mw2[t] : 0.0f;
    }
    if (t < HDIM * OUT_DIM) {
        int i = t / OUT_DIM, o = t - i * OUT_DIM;
        mwom[t] = ((o / 6) > (i % 7)) ? mwo[t] : 0.0f;
    }
}

// ---------------- Stage A: KNN + local-frame gather ----------------
__global__ __launch_bounds__(256) void knn_kernel(const float* __restrict__ coords,
                                                  float* __restrict__ flat) {
    const int b = blockIdx.y;
    const int q0 = blockIdx.x * QB;
    const int tid = threadIdx.x;
    const int lane = tid & 63;   // query within block
    const int w = tid >> 6;      // slice id

    __shared__ f4 pts[NPT];                    // {x,y,z,|p|^2} 16 KB
    __shared__ ull cand[NSL][QB][TOPK + 1];    // +1 sentinel    28 KB

    const float* cb = coords + (size_t)b * NPT * 3;
    for (int i = tid; i < NPT; i += QB * NSL) {
        float x = cb[3 * i + 0], y = cb[3 * i + 1], z = cb[3 * i + 2];
        f4 v; v[0] = x; v[1] = y; v[2] = z; v[3] = x * x + y * y + z * z;
        pts[i] = v;
    }
    __syncthreads();

    const int q = q0 + lane;
    const f4 C = pts[q];
    const float cx = C[0], cy = C[1], cz = C[2], sq_q = C[3];

    ull best[TOPK];
#pragma unroll
    for (int k = 0; k < TOPK; ++k) best[k] = ~0ull;

    const int jbase = w * SLICE;
    for (int t = 0; t < SLICE; ++t) {
        int j = jbase + t;
        f4 P = pts[j];
        float dot = cx * P[0] + cy * P[1] + cz * P[2];
        float d = sq_q + P[3] - 2.0f * dot;    // reference formula
        ull key = ((ull)mono(d) << 32) | (unsigned)j;
        if (key < best[TOPK - 1]) {
            ull carry = key;
#pragma unroll
            for (int k = 0; k < TOPK; ++k) {
                ull old = best[k];
                ull lo = (old < carry) ? old : carry;
                carry   = (old < carry) ? carry : old;
                best[k] = lo;
            }
        }
    }
#pragma unroll
    for (int k = 0; k < TOPK; ++k) cand[w][lane][k] = best[k];
    cand[w][lane][TOPK] = ~0ull;   // sentinel
    __syncthreads();

    // 4-way merge, one thread per query
    if (tid < QB) {
        const int mq = tid;
        const f4 MC = pts[q0 + mq];
        float* o = flat + (size_t)(b * NPT + q0 + mq) * IN_DIM;
        int h0 = 0, h1 = 0, h2 = 0, h3 = 0;
        for (int k = 0; k < TOPK; ++k) {
            ull v0 = cand[0][mq][h0], v1 = cand[1][mq][h1];
            ull v2 = cand[2][mq][h2], v3 = cand[3][mq][h3];
            ull m01 = v0 < v1 ? v0 : v1;
            ull m23 = v2 < v3 ? v2 : v3;
            ull m = m01 < m23 ? m01 : m23;
            h0 += (v0 == m); h1 += (v1 == m); h2 += (v2 == m); h3 += (v3 == m);
            if (k > 0) {                         // k==0 matches reference idx[:,:,1:] drop
                int j = (int)(m & 0xFFFFFFFFull);
                f4 P = pts[j];
                o[(k - 1) * 3 + 0] = P[0] - MC[0];
                o[(k - 1) * 3 + 1] = P[1] - MC[1];
                o[(k - 1) * 3 + 2] = P[2] - MC[2];
            }
        }
    }
}

// ---------------- Stage B: fused MLP + MADE + combine ----------------
// SPILL FIX vs R6: (a) no min-waves in launch_bounds (allocator uncapped);
// (b) h-path and g-path computed in SEQUENTIAL passes (half the live
// accumulators/weight streams); (c) #pragma unroll 2 bounds the i-loop
// unroll so load hoisting can't blow up live ranges.
template <bool PM>
__global__ __launch_bounds__(128) void mlp_kernel(
    const float* __restrict__ flat, const float* __restrict__ coords,
    const float* __restrict__ w_h1, const float* __restrict__ b_h1,
    const float* __restrict__ w_h2, const float* __restrict__ b_h2,
    const float* __restrict__ w_h3, const float* __restrict__ b_h3,
    const float* __restrict__ w_bp, const float* __restrict__ b_bp,
    const float* __restrict__ cw,  const float* __restrict__ mb1,
    const float* __restrict__ mw2x, const float* __restrict__ mb2,
    const float* __restrict__ mwox, const float* __restrict__ mbo,
    float* __restrict__ out) {
    const int p0g = blockIdx.x * PTILE;
    const int tid = threadIdx.x;
    const int ng = tid & 31, pg = tid >> 5;
    const int j0 = ng * 4;
    const int pA = pg * 2;

    __shared__ float A[PTILE][HPAD];   // hA, then h3
    __shared__ float B[PTILE][HPAD];   // gA
    __shared__ float Cb[PTILE][HPAD];  // x (aliased), then hB
    __shared__ float D[PTILE][HPAD];   // gB

    float* xbuf = &Cb[0][0];           // [PTILE][IN_DIM] packed, dead before Cb written
    {
        const f4* src = (const f4*)(flat + (size_t)p0g * IN_DIM);
        f4* dst = (f4*)xbuf;
        for (int u = tid; u < PTILE * IN_DIM / 4; u += 128) dst[u] = src[u];
    }
    __syncthreads();   // (1) x staged

    // ---- layer 1: h pass, then g pass (sequential -> low reg pressure) ----
    f4 h0, h1, g0, g1;
    {
        f4 a0 = *(const f4*)&b_h1[j0], a1 = a0;
#pragma unroll 2
        for (int i = 0; i < IN_DIM; i += 4) {
            f4 xa = *(const f4*)&xbuf[(pA + 0) * IN_DIM + i];
            f4 xb = *(const f4*)&xbuf[(pA + 1) * IN_DIM + i];
#pragma unroll
            for (int u = 0; u < 4; ++u) {
                f4 wh = *(const f4*)&w_h1[(i + u) * HDIM + j0];
                a0 += xa[u] * wh; a1 += xb[u] * wh;
            }
        }
        h0 = a0; h1 = a1;
    }
    {
        f4 a0 = *(const f4*)&mb1[j0], a1 = a0;
#pragma unroll 2
        for (int i = 0; i < IN_DIM; i += 4) {
            f4 xa = *(const f4*)&xbuf[(pA + 0) * IN_DIM + i];
            f4 xb = *(const f4*)&xbuf[(pA + 1) * IN_DIM + i];
#pragma unroll
            for (int u = 0; u < 4; ++u) {
                f4 wg = *(const f4*)&cw[(i + u) * HDIM + j0];
                a0 += xa[u] * wg; a1 += xb[u] * wg;
            }
        }
        g0 = a0; g1 = a1;
    }
    {
        f4 r0, r1, t0, t1;
#pragma unroll
        for (int u = 0; u < 4; ++u) {
            r0[u] = fmaxf(h0[u], 0.0f); r1[u] = fmaxf(h1[u], 0.0f);
            t0[u] = tanhf(g0[u]);       t1[u] = tanhf(g1[u]);
        }
        *(f4*)&A[pA + 0][j0] = r0; *(f4*)&A[pA + 1][j0] = r1;
        *(f4*)&B[pA + 0][j0] = t0; *(f4*)&B[pA + 1][j0] = t1;
    }
    __syncthreads();   // (2) A,B visible; all xbuf reads complete

    // ---- layer 2: h pass (A), then masked g pass (B) ----
    {
        f4 a0 = *(const f4*)&b_h2[j0], a1 = a0;
#pragma unroll 2
        for (int i = 0; i < HDIM; i += 4) {
            f4 xa = *(const f4*)&A[pA + 0][i];
            f4 xb = *(const f4*)&A[pA + 1][i];
#pragma unroll
            for (int u = 0; u < 4; ++u) {
                f4 wh = *(const f4*)&w_h2[(i + u) * HDIM + j0];
                a0 += xa[u] * wh; a1 += xb[u] * wh;
            }
        }
        h0 = a0; h1 = a1;
    }
    {
        f4 a0 = *(const f4*)&mb2[j0], a1 = a0;
#pragma unroll 2
        for (int i = 0; i < HDIM; i += 4) {
            f4 xa = *(const f4*)&B[pA + 0][i];
            f4 xb = *(const f4*)&B[pA + 1][i];
#pragma unroll
            for (int u = 0; u < 4; ++u) {
                f4 wg = *(const f4*)&mw2x[(i + u) * HDIM + j0];
                if (!PM) {
                    int r = (i + u) % 7;   // m2[i][j] = (j%7 >= i%7)
#pragma unroll
                    for (int c = 0; c < 4; ++c)
                        wg[c] = (((j0 + c) % 7) >= r) ? wg[c] : 0.0f;
                }
                a0 += xa[u] * wg; a1 += xb[u] * wg;
            }
        }
        g0 = a0; g1 = a1;
    }
    __syncthreads();   // (3) all A/B (and earlier xbuf) reads done before overwrite
    {
        f4 r0, r1, t0, t1;
#pragma unroll
        for (int u = 0; u < 4; ++u) {
            r0[u] = fmaxf(h0[u], 0.0f); r1[u] = fmaxf(h1[u], 0.0f);
            t0[u] = tanhf(g0[u]);       t1[u] = tanhf(g1[u]);
        }
        *(f4*)&Cb[pA + 0][j0] = r0; *(f4*)&Cb[pA + 1][j0] = r1;
        *(f4*)&D[pA + 0][j0]  = t0; *(f4*)&D[pA + 1][j0]  = t1;
    }
    __syncthreads();   // (4) Cb(hB), D(gB) visible

    // ---- layer 3 (h only): reads Cb, writes A (safe: A reads ended pre-(3)) ----
    {
        f4 a0 = *(const f4*)&b_h3[j0], a1 = a0;
#pragma unroll 2
        for (int i = 0; i < HDIM; i += 4) {
            f4 xa = *(const f4*)&Cb[pA + 0][i];
            f4 xb = *(const f4*)&Cb[pA + 1][i];
#pragma unroll
            for (int u = 0; u < 4; ++u) {
                f4 wh = *(const f4*)&w_h3[(i + u) * HDIM + j0];
                a0 += xa[u] * wh; a1 += xb[u] * wh;
            }
        }
#pragma unroll
        for (int u = 0; u < 4; ++u) { a0[u] = fmaxf(a0[u], 0.0f); a1[u] = fmaxf(a1[u], 0.0f); }
        *(f4*)&A[pA + 0][j0] = a0;
        *(f4*)&A[pA + 1][j0] = a1;
    }
    __syncthreads();   // (5) h3 visible

    // ---- heads + combine: thread = (pq 0..7) x (og 0..15), outputs o0..o0+2 ----
    {
        const int og = tid & 15, pq = tid >> 4;
        const int o0 = og * 3;
        const int dego0 = (o0 + 0) / 6, dego1 = (o0 + 1) / 6, dego2 = (o0 + 2) / 6;
        float ap[3], as[3];
#pragma unroll
        for (int t = 0; t < 3; ++t) { ap[t] = b_bp[o0 + t]; as[t] = mbo[o0 + t]; }
#pragma unroll 2
        for (int i = 0; i < HDIM; i += 4) {
            f4 hv = *(const f4*)&A[pq][i];
            f4 gv = *(const f4*)&D[pq][i];
#pragma unroll
            for (int u = 0; u < 4; ++u) {
                float ws0 = mwox[(i + u) * OUT_DIM + o0 + 0];
                float ws1 = mwox[(i + u) * OUT_DIM + o0 + 1];
                float ws2 = mwox[(i + u) * OUT_DIM + o0 + 2];
                if (!PM) {
                    int r = (i + u) % 7;   // mo[i][o] = (o/6 > i%7)
                    ws0 = (dego0 > r) ? ws0 : 0.0f;
                    ws1 = (dego1 > r) ? ws1 : 0.0f;
                    ws2 = (dego2 > r) ? ws2 : 0.0f;
                }
                ap[0] = fmaf(hv[u], w_bp[(i + u) * OUT_DIM + o0 + 0], ap[0]);
                ap[1] = fmaf(hv[u], w_bp[(i + u) * OUT_DIM + o0 + 1], ap[1]);
                ap[2] = fmaf(hv[u], w_bp[(i + u) * OUT_DIM + o0 + 2], ap[2]);
                as[0] = fmaf(gv[u], ws0, as[0]);
                as[1] = fmaf(gv[u], ws1, as[1]);
                as[2] = fmaf(gv[u], ws2, as[2]);
            }
        }
        const float* cpt = &coords[(size_t)(p0g + pq) * 3];
        float c0 = cpt[0], c1 = cpt[1], c2 = cpt[2];
        float* op = out + (size_t)(p0g + pq) * OUT_DIM;
#pragma unroll
        for (int t = 0; t < 3; ++t) {
            int o = o0 + t;
            float v = ap[t] + as[t];
            float r;
            if (o & 1) {
                r = expf(0.5f * v);
            } else {
                int d = (o % 6) >> 1;
                float cv = (d == 0) ? c0 : (d == 1) ? c1 : c2;
                r = cv + v;
            }
            op[o] = r;
        }
    }
}

extern "C" void kernel_launch(void* const* d_in, const int* in_sizes, int n_in,
                              void* d_out, int out_size, void* d_ws, size_t ws_size,
                              hipStream_t stream) {
    const float* coords = (const float*)d_in[0];
    const float* w_h1 = (const float*)d_in[1];
    const float* b_h1 = (const float*)d_in[2];
    const float* w_h2 = (const float*)d_in[3];
    const float* b_h2 = (const float*)d_in[4];
    const float* w_h3 = (const float*)d_in[5];
    const float* b_h3 = (const float*)d_in[6];
    const float* w_bp = (const float*)d_in[7];
    const float* b_bp = (const float*)d_in[8];
    const float* cw   = (const float*)d_in[9];
    // d_in[10] = mw1: dead (x0 == 0)
    const float* mb1  = (const float*)d_in[11];
    const float* mw2  = (const float*)d_in[12];
    const float* mb2  = (const float*)d_in[13];
    const float* mwo  = (const float*)d_in[14];
    const float* mbo  = (const float*)d_in[15];
    float* out = (float*)d_out;

    char* ws = (char*)d_ws;
    const size_t FLAT_BYTES = (size_t)NB * NPT * IN_DIM * 4;      // 4718592
    const size_t MW2M_BYTES = HDIM * HDIM * 4;                    // 65536
    const size_t MWOM_BYTES = HDIM * OUT_DIM * 4;                 // 24576
    float* flat = (float*)ws;
    const bool pm = ws_size >= FLAT_BYTES + MW2M_BYTES + MWOM_BYTES;  // constant per run

    dim3 gA(NPT / QB, NB);
    knn_kernel<<<gA, QB * NSL, 0, stream>>>(coords, flat);

    const int nblocks = (NB * NPT) / PTILE;                 // 4096
    if (pm) {
        float* mw2m = (float*)(ws + FLAT_BYTES);
        float* mwom = (float*)(ws + FLAT_BYTES + MW2M_BYTES);
        premask_kernel<<<(HDIM * HDIM + 255) / 256, 256, 0, stream>>>(mw2, mwo, mw2m, mwom);
        mlp_kernel<true><<<nblocks, 128, 0, stream>>>(flat, coords,
                                                      w_h1, b_h1, w_h2, b_h2, w_h3, b_h3,
                                                      w_bp, b_bp, cw, mb1, mw2m, mb2, mwom, mbo,
                                                      out);
    } else {
        mlp_kernel<false><<<nblocks, 128, 0, stream>>>(flat, coords,
                                                       w_h1, b_h1, w_h2, b_h2, w_h3, b_h3,
                                                       w_bp, b_bp, cw, mb1, mw2, mb2, mwo, mbo,
                                                       out);
    }
}